// Round 5
// baseline (248.300 us; speedup 1.0000x reference)
//
#include <hip/hip_runtime.h>
#include <hip/hip_cooperative_groups.h>

namespace cg = cooperative_groups;

// GAT layer: B=16, N=1024, IN_DIM=128, H=4, D=64, neg_slope=0.2
// R5 model: ALL float tensors are fp32 (per the reference), adj int32,
// out fp32 (16 MB). R1-R4 read inputs as bf16 -> mantissa-bit garbage ->
// +/-inf partial sums -> NaN. Core math unchanged (hand-verified 3x).
//
// Single cooperative kernel, NO d_ws use. d_out (16 MB) doubles as scratch
// between grid syncs:
//   hT bf16   @ float ofs 0        (8 MB)   h transposed [b][h][d][n]
//   e_srcT    @ float ofs 2097152  (256 KB)
//   e_dstT    @ float ofs 2162688  (256 KB)
//   adjbits   @ float ofs 2228224  (128 KB) 1 bit per (i,j)
// Phase A: pack adj bits; h = x@W (fp32), store bf16 hT + fp32 e_src/e_dst
// grid.sync()
// Phase B: flash-style masked-softmax aggregation, MFMA 16x16x32 bf16,
//          results in registers
// grid.sync()
// Phase C: normalized fp32 epilogue overwrites d_out

#define B_  16
#define N_  1024
#define IND 128
#define H_  4
#define D_  64
#define NEG 0.2f

typedef __attribute__((ext_vector_type(8))) short short8;
typedef __attribute__((ext_vector_type(4))) float float4v;

static __device__ __forceinline__ unsigned short f2bf(float f) {
  unsigned int u = __float_as_uint(f);
  u += 0x7fffu + ((u >> 16) & 1u);   // RNE, finite only
  return (unsigned short)(u >> 16);
}

__global__ __launch_bounds__(256) void k_gat(const float* x, const int* adj,
                                             const float* W, const float* a_src,
                                             const float* a_dst, float* out) {
  __shared__ float xls[IND * 8];                 // 4 KB, [k][r]
  __shared__ float e_lds[H_][N_];                // 16 KB
  __shared__ float es_lds[H_][64];               // 1 KB
  __shared__ unsigned int adj_lds[64 * 33];      // 8.25 KB, padded

  const int g = blockIdx.x;                      // 256 blocks = 16 b x 16 i-tiles
  const int t = threadIdx.x;
  const int l = t & 63;
  const int wv = t >> 6;                         // wave id = head id

  unsigned short* hT = reinterpret_cast<unsigned short*>(out);
  float* e_srcT = out + 2097152;
  float* e_dstT = out + 2162688;
  unsigned int* adjb = reinterpret_cast<unsigned int*>(out + 2228224);

  // ================= PHASE A0: pack adj bits =================
#pragma unroll 4
  for (int q = 0; q < 16; ++q) {
    int f = g * 4096 + q * 256 + t;              // covers 1M entries
    unsigned long long m = __ballot(adj[f] > 0); // wave spans 64 consecutive j
    if (l == 0) {
      adjb[(f >> 5)] = (unsigned int)m;
      adjb[(f >> 5) + 1] = (unsigned int)(m >> 32);
    }
  }

  // ================= PHASE A: projection + e =================
  const int hh = wv, d = l;                      // this thread owns col hh*64+d = t
  const float asv = a_src[t];                    // a_src[hh][d]
  const float adv = a_dst[t];
  for (int u = 0; u < 8; ++u) {
    const int vb = g * 8 + u;                    // 2048 tiles of 8 rows
    const int b = vb >> 7;
    const int n0 = (vb & 127) * 8;
    {
      const float4v v = reinterpret_cast<const float4v*>(x + (size_t)(b * N_ + n0) * IND)[t];
      int e0 = t * 4;
      int r = e0 >> 7, k = e0 & 127;             // transpose to [k][r]
      float* dst = &xls[k * 8 + r];
      dst[0] = v.x; dst[8] = v.y; dst[16] = v.z; dst[24] = v.w;
    }
    __syncthreads();

    float acc[8] = {0.f, 0.f, 0.f, 0.f, 0.f, 0.f, 0.f, 0.f};
#pragma unroll 4
    for (int k = 0; k < IND; ++k) {
      float wval = W[k * 256 + t];               // coalesced, L2-hot (128 KB)
      const float4v x0 = *reinterpret_cast<const float4v*>(&xls[k * 8]);     // broadcast
      const float4v x1 = *reinterpret_cast<const float4v*>(&xls[k * 8 + 4]);
      acc[0] += x0.x * wval; acc[1] += x0.y * wval; acc[2] += x0.z * wval; acc[3] += x0.w * wval;
      acc[4] += x1.x * wval; acc[5] += x1.y * wval; acc[6] += x1.z * wval; acc[7] += x1.w * wval;
    }

    short8 hs;
#pragma unroll
    for (int r = 0; r < 8; ++r) hs[r] = (short)f2bf(acc[r]);
    *reinterpret_cast<short8*>(hT + ((size_t)(b * H_ + hh) * D_ + d) * N_ + n0) = hs;

#pragma unroll
    for (int r = 0; r < 8; ++r) {                // e dots over d (wave = head)
      float es = acc[r] * asv;
      float ed = acc[r] * adv;
#pragma unroll
      for (int m = 1; m < 64; m <<= 1) {
        es += __shfl_xor(es, m, 64);
        ed += __shfl_xor(ed, m, 64);
      }
      if (d == 0) {
        e_srcT[(b * H_ + hh) * N_ + n0 + r] = es;
        e_dstT[(b * H_ + hh) * N_ + n0 + r] = ed;
      }
    }
    __syncthreads();                             // xls reused next u
  }

  cg::this_grid().sync();

  // ================= PHASE B: attention =================
  const int w = wv;
  const int quad = l >> 4;
  const int ln = l & 15;
  const int b = g >> 4;
  const int i0 = (g & 15) * 64;

  // stage adj bitmask rows i0..i0+63 (2048 words)
#pragma unroll
  for (int q = 0; q < 8; ++q) {
    int idx = q * 256 + t;
    int r = idx >> 5, c = idx & 31;
    adj_lds[r * 33 + c] = adjb[(i0 + r) * 32 + c];
  }
  // stage e_dst (head slab) + e_src (own 64 rows)
  {
    const float4v* src = reinterpret_cast<const float4v*>(e_dstT + (size_t)(b * H_ + w) * N_);
    float4v* dst = reinterpret_cast<float4v*>(&e_lds[w][0]);
#pragma unroll
    for (int q = 0; q < 4; ++q) dst[q * 64 + l] = src[q * 64 + l];
    es_lds[w][l] = e_srcT[(size_t)(b * H_ + w) * N_ + i0 + l];
  }
  __syncthreads();

  float c[4];
#pragma unroll
  for (int it = 0; it < 4; ++it) c[it] = es_lds[w][it * 16 + ln];

  const unsigned short* slab = hT + (size_t)(b * H_ + w) * D_ * N_;
  const unsigned short* hb = slab + ln * N_;
  float4v acc[4][4];
#pragma unroll
  for (int it = 0; it < 4; ++it)
#pragma unroll
    for (int dt = 0; dt < 4; ++dt) acc[it][dt] = (float4v){0.f, 0.f, 0.f, 0.f};
  float ds[4] = {0.f, 0.f, 0.f, 0.f};

  for (int j0 = 0; j0 < N_; j0 += 32) {
    const float* ep = &e_lds[w][j0 + quad * 8];
    float4v e0 = *reinterpret_cast<const float4v*>(ep);
    float4v e1 = *reinterpret_cast<const float4v*>(ep + 4);
    float ej[8] = {e0.x, e0.y, e0.z, e0.w, e1.x, e1.y, e1.z, e1.w};
    unsigned int aw[4];
#pragma unroll
    for (int it = 0; it < 4; ++it) aw[it] = adj_lds[(it * 16 + ln) * 33 + (j0 >> 5)];
    short8 afr[4];
#pragma unroll
    for (int it = 0; it < 4; ++it) {
#pragma unroll
      for (int jj = 0; jj < 8; ++jj) {
        float s = c[it] + ej[jj];
        s = fmaxf(s, NEG * s);                   // leaky relu
        s = fminf(s, 30.f);                      // safety clamp
        float p = ((aw[it] >> (quad * 8 + jj)) & 1u) ? __expf(s) : 0.f;
        ds[it] += p;
        afr[it][jj] = (short)f2bf(p);            // A-frag: row=ln, k=quad*8+jj
      }
    }
#pragma unroll
    for (int dt = 0; dt < 4; ++dt) {
      // B-frag: n=ln -> d=dt*16+ln, k=quad*8+jj -> j=j0+quad*8+jj
      short8 bv = *reinterpret_cast<const short8*>(hb + dt * 16 * N_ + j0 + quad * 8);
#pragma unroll
      for (int it = 0; it < 4; ++it)
        acc[it][dt] = __builtin_amdgcn_mfma_f32_16x16x32_bf16(afr[it], bv, acc[it][dt], 0, 0, 0);
    }
  }

  float inv[4][4];
#pragma unroll
  for (int it = 0; it < 4; ++it) {
    float d2 = ds[it] + __shfl_xor(ds[it], 16, 64);
    d2 += __shfl_xor(d2, 32, 64);                // all quads summed
#pragma unroll
    for (int r = 0; r < 4; ++r)
      inv[it][r] = 1.0f / fmaxf(__shfl(d2, quad * 4 + r, 64), 1e-30f);
  }

  cg::this_grid().sync();                        // all scratch reads complete

  // ================= PHASE C: epilogue =================
#pragma unroll
  for (int it = 0; it < 4; ++it) {
#pragma unroll
    for (int dt = 0; dt < 4; ++dt) {
#pragma unroll
      for (int r = 0; r < 4; ++r) {
        int row = i0 + it * 16 + quad * 4 + r;   // C-layout: row=quad*4+reg, col=ln
        int col = w * 64 + dt * 16 + ln;
        out[(size_t)(b * N_ + row) * 256 + col] = acc[it][dt][r] * inv[it][r];
      }
    }
  }
}

extern "C" void kernel_launch(void* const* d_in, const int* in_sizes, int n_in,
                              void* d_out, int out_size, void* d_ws, size_t ws_size,
                              hipStream_t stream) {
  const float* x = (const float*)d_in[0];
  const int* adj = (const int*)d_in[1];
  const float* W = (const float*)d_in[2];
  const float* a_src = (const float*)d_in[3];
  const float* a_dst = (const float*)d_in[4];
  float* outp = (float*)d_out;
  (void)d_ws; (void)ws_size;

  void* args[] = {(void*)&x, (void*)&adj, (void*)&W, (void*)&a_src, (void*)&a_dst, (void*)&outp};
  hipLaunchCooperativeKernel((void*)k_gat, dim3(256), dim3(256), args, 0u, stream);
}

// Round 7
// 134.615 us; speedup vs baseline: 1.8445x; 1.8445x over previous
//
#include <hip/hip_runtime.h>
#include <hip/hip_cooperative_groups.h>

namespace cg = cooperative_groups;

// GAT layer: B=16, N=1024, IN_DIM=128, H=4, D=64, neg_slope=0.2
// Inputs fp32 (x, W, a_src, a_dst), adj int32, out fp32 (confirmed R5 PASS).
//
// R7 = R6 with the x-transpose store stride fixed (was 9/18/27, must be
// 8/16/24: within a 4-group of k the padded stride is still 8; the +4 pad
// applies only between 4-groups). R6's finite-wrong output confirmed
// ws_size >= 9 MB and isolated the bug to the staged x tile.
//
// Split path:
//   k_proj (2048 blks): adj bit-pack + h=x@W fp32 + e_src/e_dst dots.
//     hT stored bf16 SWIZZLED [b][h][jb][d][jo] (n=jb*8+jo): proj store and
//     attn B-frag load are both contiguous 1KB/wave.
//   k_attn (512 blks, 32-row tiles): flash-style masked softmax + MFMA PV.
// Fallback: R5 cooperative kernel (verbatim) if ws too small.
// ws layout: hT @0 (8MB) | e_srcT @8388608 | e_dstT @8650752 | adjb @8912896

#define B_  16
#define N_  1024
#define IND 128
#define H_  4
#define D_  64
#define NEG 0.2f

typedef __attribute__((ext_vector_type(8))) short short8;
typedef __attribute__((ext_vector_type(4))) float float4v;

static __device__ __forceinline__ unsigned short f2bf(float f) {
  unsigned int u = __float_as_uint(f);
  u += 0x7fffu + ((u >> 16) & 1u);   // RNE, finite only
  return (unsigned short)(u >> 16);
}
// padded x-transpose LDS addressing: row k base = k*8 + (k>>2)*4.
// Within a 4-group (k multiple of 4 at store site) stride is 8.
static __device__ __forceinline__ int xla(int k) { return k * 8 + (k >> 2) * 4; }

// ================= split path =================
__global__ __launch_bounds__(256) void k_proj(const float* __restrict__ x,
                                              const int* __restrict__ adj,
                                              const float* __restrict__ W,
                                              const float* __restrict__ a_src,
                                              const float* __restrict__ a_dst,
                                              unsigned short* __restrict__ hT,
                                              float* __restrict__ e_srcT,
                                              float* __restrict__ e_dstT,
                                              unsigned int* __restrict__ adjb) {
  __shared__ float xls[IND * 8 + IND];           // 4.5 KB padded
  const int g = blockIdx.x;                      // 2048 blocks: 16 b * 128 tiles
  const int t = threadIdx.x;
  const int l = t & 63;
  const int b = g >> 7;
  const int jb = g & 127;                        // row-tile = swizzle block
  const int n0 = jb * 8;

  // ---- adj bit-pack: 2 ballot groups per block covers 1M entries ----
#pragma unroll
  for (int q = 0; q < 2; ++q) {
    int f = g * 512 + q * 256 + t;
    unsigned long long m = __ballot(adj[f] > 0);
    if (l == 0) {
      adjb[(f >> 5)] = (unsigned int)m;
      adjb[(f >> 5) + 1] = (unsigned int)(m >> 32);
    }
  }

  // ---- stage 8 x-rows transposed to [k][r] ----
  {
    const float4v v = reinterpret_cast<const float4v*>(x + (size_t)(b * N_ + n0) * IND)[t];
    int e0 = t * 4;
    int r = e0 >> 7, k = e0 & 127;               // k multiple of 4
    float* dst = &xls[xla(k) + r];
    dst[0] = v.x; dst[8] = v.y; dst[16] = v.z; dst[24] = v.w;  // intra-group stride 8
  }
  __syncthreads();

  float acc[8] = {0.f, 0.f, 0.f, 0.f, 0.f, 0.f, 0.f, 0.f};
#pragma unroll 4
  for (int k = 0; k < IND; ++k) {
    float wval = W[k * 256 + t];                 // coalesced, L2-hot
    const float4v x0 = *reinterpret_cast<const float4v*>(&xls[xla(k)]);
    const float4v x1 = *reinterpret_cast<const float4v*>(&xls[xla(k) + 4]);
    acc[0] += x0.x * wval; acc[1] += x0.y * wval; acc[2] += x0.z * wval; acc[3] += x0.w * wval;
    acc[4] += x1.x * wval; acc[5] += x1.y * wval; acc[6] += x1.z * wval; acc[7] += x1.w * wval;
  }

  const int hh = t >> 6, d = l;                  // owns col hh*64+d = t
  short8 hs;
#pragma unroll
  for (int r = 0; r < 8; ++r) hs[r] = (short)f2bf(acc[r]);
  // swizzled store: [b][h][jb][d][jo], contiguous 1 KB per wave
  *reinterpret_cast<short8*>(hT + ((size_t)(b * H_ + hh) * 128 + jb) * 512 + d * 8) = hs;

  const float asv = a_src[t];
  const float adv = a_dst[t];
#pragma unroll
  for (int r = 0; r < 8; ++r) {
    float es = acc[r] * asv;
    float ed = acc[r] * adv;
#pragma unroll
    for (int m = 1; m < 64; m <<= 1) {
      es += __shfl_xor(es, m, 64);
      ed += __shfl_xor(ed, m, 64);
    }
    if (d == 0) {
      e_srcT[(b * H_ + hh) * N_ + n0 + r] = es;
      e_dstT[(b * H_ + hh) * N_ + n0 + r] = ed;
    }
  }
}

__global__ __launch_bounds__(256) void k_attn(const unsigned short* __restrict__ hT,
                                              const float* __restrict__ e_srcT,
                                              const float* __restrict__ e_dstT,
                                              const unsigned int* __restrict__ adjb,
                                              float* __restrict__ out) {
  __shared__ float e_lds[H_][N_];                // 16 KB
  __shared__ float es_lds[H_][32];               // 512 B
  __shared__ unsigned int adj_lds[32 * 33];      // 4.2 KB padded

  const int t = threadIdx.x;
  const int w = t >> 6;                          // head = wave
  const int l = t & 63;
  const int quad = l >> 4;
  const int ln = l & 15;
  const int b = blockIdx.x >> 5;                 // 512 blocks: 16 b * 32 i-tiles
  const int i0 = (blockIdx.x & 31) * 32;

  // stage adj bitmask rows i0..i0+31
#pragma unroll
  for (int q = 0; q < 4; ++q) {
    int idx = q * 256 + t;
    int r = idx >> 5, c2 = idx & 31;
    adj_lds[r * 33 + c2] = adjb[(i0 + r) * 32 + c2];
  }
  // stage e_dst (own head, all j) + e_src (own 32 rows)
  {
    const float4v* src = reinterpret_cast<const float4v*>(e_dstT + (size_t)(b * H_ + w) * N_);
    float4v* dst = reinterpret_cast<float4v*>(&e_lds[w][0]);
#pragma unroll
    for (int q = 0; q < 4; ++q) dst[q * 64 + l] = src[q * 64 + l];
    if (l < 32) es_lds[w][l] = e_srcT[(size_t)(b * H_ + w) * N_ + i0 + l];
  }
  __syncthreads();

  float c[2];
#pragma unroll
  for (int it = 0; it < 2; ++it) c[it] = es_lds[w][it * 16 + ln];

  const unsigned short* slab = hT + (size_t)(b * H_ + w) * 65536;
  const int doff = (quad * 512) + ln * 8;        // + (j0>>3)*512 + dt*128 at use
  float4v acc[2][4];
#pragma unroll
  for (int it = 0; it < 2; ++it)
#pragma unroll
    for (int dt = 0; dt < 4; ++dt) acc[it][dt] = (float4v){0.f, 0.f, 0.f, 0.f};
  float ds[2] = {0.f, 0.f};

  for (int j0 = 0; j0 < N_; j0 += 32) {
    const float* ep = &e_lds[w][j0 + quad * 8];
    float4v e0 = *reinterpret_cast<const float4v*>(ep);
    float4v e1 = *reinterpret_cast<const float4v*>(ep + 4);
    float ej[8] = {e0.x, e0.y, e0.z, e0.w, e1.x, e1.y, e1.z, e1.w};
    unsigned int aw[2];
#pragma unroll
    for (int it = 0; it < 2; ++it) aw[it] = adj_lds[(it * 16 + ln) * 33 + (j0 >> 5)];
    short8 afr[2];
#pragma unroll
    for (int it = 0; it < 2; ++it) {
#pragma unroll
      for (int jj = 0; jj < 8; ++jj) {
        float s = c[it] + ej[jj];
        s = fmaxf(s, NEG * s);                   // leaky relu
        s = fminf(s, 30.f);                      // safety clamp
        float p = ((aw[it] >> (quad * 8 + jj)) & 1u) ? __expf(s) : 0.f;
        ds[it] += p;
        afr[it][jj] = (short)f2bf(p);            // A-frag: row=ln, k=quad*8+jj
      }
    }
    // B-frag loads: swizzled layout -> contiguous 1KB/wave per instr
    const unsigned short* jbase = slab + (size_t)(j0 >> 3) * 512;
#pragma unroll
    for (int dt = 0; dt < 4; ++dt) {
      short8 bv = *reinterpret_cast<const short8*>(jbase + doff + dt * 128);
#pragma unroll
      for (int it = 0; it < 2; ++it)
        acc[it][dt] = __builtin_amdgcn_mfma_f32_16x16x32_bf16(afr[it], bv, acc[it][dt], 0, 0, 0);
    }
  }

  float inv[2][4];
#pragma unroll
  for (int it = 0; it < 2; ++it) {
    float d2 = ds[it] + __shfl_xor(ds[it], 16, 64);
    d2 += __shfl_xor(d2, 32, 64);
#pragma unroll
    for (int r = 0; r < 4; ++r)
      inv[it][r] = 1.0f / fmaxf(__shfl(d2, quad * 4 + r, 64), 1e-30f);
  }

#pragma unroll
  for (int it = 0; it < 2; ++it) {
#pragma unroll
    for (int dt = 0; dt < 4; ++dt) {
#pragma unroll
      for (int r = 0; r < 4; ++r) {
        int row = i0 + it * 16 + quad * 4 + r;   // C-layout: row=quad*4+reg, col=ln
        int col = w * 64 + dt * 16 + ln;
        out[(size_t)(b * N_ + row) * 256 + col] = acc[it][dt][r] * inv[it][r];
      }
    }
  }
}

// ================= cooperative fallback (R5, verbatim) =================
__global__ __launch_bounds__(256) void k_gat(const float* x, const int* adj,
                                             const float* W, const float* a_src,
                                             const float* a_dst, float* out) {
  __shared__ float xls[IND * 8];
  __shared__ float e_lds[H_][N_];
  __shared__ float es_lds[H_][64];
  __shared__ unsigned int adj_lds[64 * 33];

  const int g = blockIdx.x;
  const int t = threadIdx.x;
  const int l = t & 63;
  const int wv = t >> 6;

  unsigned short* hT = reinterpret_cast<unsigned short*>(out);
  float* e_srcT = out + 2097152;
  float* e_dstT = out + 2162688;
  unsigned int* adjb = reinterpret_cast<unsigned int*>(out + 2228224);

#pragma unroll 4
  for (int q = 0; q < 16; ++q) {
    int f = g * 4096 + q * 256 + t;
    unsigned long long m = __ballot(adj[f] > 0);
    if (l == 0) {
      adjb[(f >> 5)] = (unsigned int)m;
      adjb[(f >> 5) + 1] = (unsigned int)(m >> 32);
    }
  }

  const int hh = wv, d = l;
  const float asv = a_src[t];
  const float adv = a_dst[t];
  for (int u = 0; u < 8; ++u) {
    const int vb = g * 8 + u;
    const int b = vb >> 7;
    const int n0 = (vb & 127) * 8;
    {
      const float4v v = reinterpret_cast<const float4v*>(x + (size_t)(b * N_ + n0) * IND)[t];
      int e0 = t * 4;
      int r = e0 >> 7, k = e0 & 127;
      float* dst = &xls[k * 8 + r];
      dst[0] = v.x; dst[8] = v.y; dst[16] = v.z; dst[24] = v.w;
    }
    __syncthreads();

    float acc[8] = {0.f, 0.f, 0.f, 0.f, 0.f, 0.f, 0.f, 0.f};
#pragma unroll 4
    for (int k = 0; k < IND; ++k) {
      float wval = W[k * 256 + t];
      const float4v x0 = *reinterpret_cast<const float4v*>(&xls[k * 8]);
      const float4v x1 = *reinterpret_cast<const float4v*>(&xls[k * 8 + 4]);
      acc[0] += x0.x * wval; acc[1] += x0.y * wval; acc[2] += x0.z * wval; acc[3] += x0.w * wval;
      acc[4] += x1.x * wval; acc[5] += x1.y * wval; acc[6] += x1.z * wval; acc[7] += x1.w * wval;
    }

    short8 hs;
#pragma unroll
    for (int r = 0; r < 8; ++r) hs[r] = (short)f2bf(acc[r]);
    *reinterpret_cast<short8*>(hT + ((size_t)(b * H_ + hh) * D_ + d) * N_ + n0) = hs;

#pragma unroll
    for (int r = 0; r < 8; ++r) {
      float es = acc[r] * asv;
      float ed = acc[r] * adv;
#pragma unroll
      for (int m = 1; m < 64; m <<= 1) {
        es += __shfl_xor(es, m, 64);
        ed += __shfl_xor(ed, m, 64);
      }
      if (d == 0) {
        e_srcT[(b * H_ + hh) * N_ + n0 + r] = es;
        e_dstT[(b * H_ + hh) * N_ + n0 + r] = ed;
      }
    }
    __syncthreads();
  }

  cg::this_grid().sync();

  const int w = wv;
  const int quad = l >> 4;
  const int ln = l & 15;
  const int b = g >> 4;
  const int i0 = (g & 15) * 64;

#pragma unroll
  for (int q = 0; q < 8; ++q) {
    int idx = q * 256 + t;
    int r = idx >> 5, c2 = idx & 31;
    adj_lds[r * 33 + c2] = adjb[(i0 + r) * 32 + c2];
  }
  {
    const float4v* src = reinterpret_cast<const float4v*>(e_dstT + (size_t)(b * H_ + w) * N_);
    float4v* dst = reinterpret_cast<float4v*>(&e_lds[w][0]);
#pragma unroll
    for (int q = 0; q < 4; ++q) dst[q * 64 + l] = src[q * 64 + l];
    es_lds[w][l] = e_srcT[(size_t)(b * H_ + w) * N_ + i0 + l];
  }
  __syncthreads();

  float c[4];
#pragma unroll
  for (int it = 0; it < 4; ++it) c[it] = es_lds[w][it * 16 + ln];

  const unsigned short* slab = hT + (size_t)(b * H_ + w) * D_ * N_;
  const unsigned short* hb = slab + ln * N_;
  float4v acc[4][4];
#pragma unroll
  for (int it = 0; it < 4; ++it)
#pragma unroll
    for (int dt = 0; dt < 4; ++dt) acc[it][dt] = (float4v){0.f, 0.f, 0.f, 0.f};
  float ds[4] = {0.f, 0.f, 0.f, 0.f};

  for (int j0 = 0; j0 < N_; j0 += 32) {
    const float* ep = &e_lds[w][j0 + quad * 8];
    float4v e0 = *reinterpret_cast<const float4v*>(ep);
    float4v e1 = *reinterpret_cast<const float4v*>(ep + 4);
    float ej[8] = {e0.x, e0.y, e0.z, e0.w, e1.x, e1.y, e1.z, e1.w};
    unsigned int aw[4];
#pragma unroll
    for (int it = 0; it < 4; ++it) aw[it] = adj_lds[(it * 16 + ln) * 33 + (j0 >> 5)];
    short8 afr[4];
#pragma unroll
    for (int it = 0; it < 4; ++it) {
#pragma unroll
      for (int jj = 0; jj < 8; ++jj) {
        float s = c[it] + ej[jj];
        s = fmaxf(s, NEG * s);
        s = fminf(s, 30.f);
        float p = ((aw[it] >> (quad * 8 + jj)) & 1u) ? __expf(s) : 0.f;
        ds[it] += p;
        afr[it][jj] = (short)f2bf(p);
      }
    }
#pragma unroll
    for (int dt = 0; dt < 4; ++dt) {
      short8 bv = *reinterpret_cast<const short8*>(hb + dt * 16 * N_ + j0 + quad * 8);
#pragma unroll
      for (int it = 0; it < 4; ++it)
        acc[it][dt] = __builtin_amdgcn_mfma_f32_16x16x32_bf16(afr[it], bv, acc[it][dt], 0, 0, 0);
    }
  }

  float inv[4][4];
#pragma unroll
  for (int it = 0; it < 4; ++it) {
    float d2 = ds[it] + __shfl_xor(ds[it], 16, 64);
    d2 += __shfl_xor(d2, 32, 64);
#pragma unroll
    for (int r = 0; r < 4; ++r)
      inv[it][r] = 1.0f / fmaxf(__shfl(d2, quad * 4 + r, 64), 1e-30f);
  }

  cg::this_grid().sync();

#pragma unroll
  for (int it = 0; it < 4; ++it) {
#pragma unroll
    for (int dt = 0; dt < 4; ++dt) {
#pragma unroll
      for (int r = 0; r < 4; ++r) {
        int row = i0 + it * 16 + quad * 4 + r;
        int col = w * 64 + dt * 16 + ln;
        out[(size_t)(b * N_ + row) * 256 + col] = acc[it][dt][r] * inv[it][r];
      }
    }
  }
}

extern "C" void kernel_launch(void* const* d_in, const int* in_sizes, int n_in,
                              void* d_out, int out_size, void* d_ws, size_t ws_size,
                              hipStream_t stream) {
  const float* x = (const float*)d_in[0];
  const int* adj = (const int*)d_in[1];
  const float* W = (const float*)d_in[2];
  const float* a_src = (const float*)d_in[3];
  const float* a_dst = (const float*)d_in[4];
  float* outp = (float*)d_out;

  if (ws_size >= 9043968u) {
    char* ws = (char*)d_ws;
    unsigned short* hT = (unsigned short*)ws;
    float* e_srcT = (float*)(ws + 8388608);
    float* e_dstT = (float*)(ws + 8650752);
    unsigned int* adjb = (unsigned int*)(ws + 8912896);
    hipLaunchKernelGGL(k_proj, dim3(2048), dim3(256), 0, stream,
                       x, adj, W, a_src, a_dst, hT, e_srcT, e_dstT, adjb);
    hipLaunchKernelGGL(k_attn, dim3(512), dim3(256), 0, stream,
                       hT, e_srcT, e_dstT, adjb, outp);
  } else {
    void* args[] = {(void*)&x, (void*)&adj, (void*)&W, (void*)&a_src, (void*)&a_dst, (void*)&outp};
    hipLaunchCooperativeKernel((void*)k_gat, dim3(256), dim3(256), args, 0u, stream);
  }
}

// Round 9
// 118.965 us; speedup vs baseline: 2.0872x; 1.1315x over previous
//
#include <hip/hip_runtime.h>
#include <hip/hip_cooperative_groups.h>

namespace cg = cooperative_groups;

// GAT layer: B=16, N=1024, IN_DIM=128, H=4, D=64, neg_slope=0.2
// Inputs fp32, adj int32, out fp32.
//
// R9 BISECT: R8 failed at absmax 0.09 after changing BOTH kernels.
// This round: k_prep + k_proj from R8 (MFMA GEMM) + k_attn from R7
// (verbatim, known-good at absmax 0.0039). PASS => R8 bug is in the
// k_attn refactor; FAIL => bug is in k_proj.
// ws: hT @0 (8MB, bf16 swizzled [b][h][jb][d][jo]) | e_srcT @8388608 |
//     e_dstT @8650752 | adjb @8912896 (128KB) | wT @9043968 (64KB bf16 [n][k])

#define B_  16
#define N_  1024
#define IND 128
#define H_  4
#define D_  64
#define NEG 0.2f

typedef __attribute__((ext_vector_type(8))) short short8;
typedef __attribute__((ext_vector_type(4))) float float4v;
typedef __attribute__((ext_vector_type(4))) unsigned int uint4v;
typedef __attribute__((ext_vector_type(2))) unsigned int uint2v;

union S8U4 { uint4v u; short8 s; };

static __device__ __forceinline__ unsigned short f2bf(float f) {
  unsigned int u = __float_as_uint(f);
  u += 0x7fffu + ((u >> 16) & 1u);
  return (unsigned short)(u >> 16);
}
// pack two fp32 -> two bf16 (RNE) in one dword: low short = bf16(a)
static __device__ __forceinline__ unsigned pk_rne(float a, float b) {
  unsigned ua = __float_as_uint(a), ub = __float_as_uint(b);
  ua += 0x7fffu + ((ua >> 16) & 1u);
  ub += 0x7fffu + ((ub >> 16) & 1u);
  return __builtin_amdgcn_perm(ub, ua, 0x07060302);
}

// ---------------- prep: adj bit-pack + W transpose to bf16 ----------------
__global__ __launch_bounds__(256) void k_prep(const int* __restrict__ adj,
                                              const float* __restrict__ W,
                                              unsigned int* __restrict__ adjb,
                                              unsigned short* __restrict__ wT) {
  const int g = blockIdx.x, t = threadIdx.x, l = t & 63;
  if (g < 4096) {
    int f = g * 256 + t;
    unsigned long long m = __ballot(adj[f] > 0);
    if (l == 0) {
      adjb[f >> 5] = (unsigned int)m;
      adjb[(f >> 5) + 1] = (unsigned int)(m >> 32);
    }
  } else {
    int wb = g - 4096;                           // 32 blocks x 4 k-rows
#pragma unroll
    for (int i = 0; i < 4; ++i) {
      int k = wb * 4 + i;
      wT[t * 128 + k] = f2bf(W[k * 256 + t]);    // wT[n][k]
    }
  }
}

// ---------------- projection: MFMA GEMM + e dots (R8) ----------------
__global__ __launch_bounds__(256) void k_proj(const float* __restrict__ x,
                                              const float* __restrict__ a_src,
                                              const float* __restrict__ a_dst,
                                              const unsigned short* __restrict__ wT,
                                              unsigned short* __restrict__ hT,
                                              float* __restrict__ e_srcT,
                                              float* __restrict__ e_dstT) {
  __shared__ unsigned short wbuf[128 * 136];     // [n_loc][k], pad 136
  const int g = blockIdx.x, t = threadIdx.x;
  const int mt = g >> 1, nh = g & 1;             // 256 m-tiles x 2 col-halves
  const int w = t >> 6, l = t & 63, quad = l >> 4, ln = l & 15;

#pragma unroll
  for (int i = 0; i < 8; ++i) {
    int c = i * 256 + t;
    int n = c >> 4, k8 = c & 15;
    *reinterpret_cast<short8*>(&wbuf[n * 136 + k8 * 8]) =
        *reinterpret_cast<const short8*>(wT + (size_t)(nh * 128 + n) * 128 + k8 * 8);
  }
  __syncthreads();

  const int m0 = mt * 64 + w * 16;
  short8 afr[4];
#pragma unroll
  for (int ks = 0; ks < 4; ++ks) {
    const float* xp = x + (size_t)(m0 + ln) * IND + ks * 32 + quad * 8;
    float4v x0 = *reinterpret_cast<const float4v*>(xp);
    float4v x1 = *reinterpret_cast<const float4v*>(xp + 4);
    S8U4 cvt;
    cvt.u = (uint4v){pk_rne(x0.x, x0.y), pk_rne(x0.z, x0.w),
                     pk_rne(x1.x, x1.y), pk_rne(x1.z, x1.w)};
    afr[ks] = cvt.s;
  }

  float4v acc[8];
#pragma unroll
  for (int nf = 0; nf < 8; ++nf) acc[nf] = (float4v){0.f, 0.f, 0.f, 0.f};
#pragma unroll
  for (int nf = 0; nf < 8; ++nf) {
#pragma unroll
    for (int ks = 0; ks < 4; ++ks) {
      short8 bv = *reinterpret_cast<const short8*>(
          &wbuf[(nf * 16 + ln) * 136 + ks * 32 + quad * 8]);
      acc[nf] = __builtin_amdgcn_mfma_f32_16x16x32_bf16(afr[ks], bv, acc[nf], 0, 0, 0);
    }
  }

  const int m_base = m0 + quad * 4;              // C rows = quad*4 + r
  const int b = m_base >> 10, nl = m_base & 1023;
  const int jb = nl >> 3, jo = nl & 7;           // jo in {0,4}
#pragma unroll
  for (int hl = 0; hl < 2; ++hl) {
    const int h = nh * 2 + hl;
    float es[4] = {0.f, 0.f, 0.f, 0.f}, ed[4] = {0.f, 0.f, 0.f, 0.f};
#pragma unroll
    for (int n4 = 0; n4 < 4; ++n4) {
      int nf = hl * 4 + n4;
      int col = nh * 128 + nf * 16 + ln;
      float asv = a_src[col], adv = a_dst[col];
#pragma unroll
      for (int r = 0; r < 4; ++r) { es[r] += acc[nf][r] * asv; ed[r] += acc[nf][r] * adv; }
      uint2v hv;
      hv.x = pk_rne(acc[nf][0], acc[nf][1]);
      hv.y = pk_rne(acc[nf][2], acc[nf][3]);
      int d = n4 * 16 + ln;
      *reinterpret_cast<uint2v*>(hT + ((size_t)(b * H_ + h) * 128 + jb) * 512 + d * 8 + jo) = hv;
    }
#pragma unroll
    for (int r = 0; r < 4; ++r) {
#pragma unroll
      for (int msk = 1; msk < 16; msk <<= 1) {
        es[r] += __shfl_xor(es[r], msk, 64);
        ed[r] += __shfl_xor(ed[r], msk, 64);
      }
    }
    if (ln == 0) {
#pragma unroll
      for (int r = 0; r < 4; ++r) {
        e_srcT[(b * H_ + h) * N_ + nl + r] = es[r];
        e_dstT[(b * H_ + h) * N_ + nl + r] = ed[r];
      }
    }
  }
}

// ---------------- attention (R7 verbatim, known-good) ----------------
__global__ __launch_bounds__(256) void k_attn(const unsigned short* __restrict__ hT,
                                              const float* __restrict__ e_srcT,
                                              const float* __restrict__ e_dstT,
                                              const unsigned int* __restrict__ adjb,
                                              float* __restrict__ out) {
  __shared__ float e_lds[H_][N_];                // 16 KB
  __shared__ float es_lds[H_][32];               // 512 B
  __shared__ unsigned int adj_lds[32 * 33];      // 4.2 KB padded

  const int t = threadIdx.x;
  const int w = t >> 6;                          // head = wave
  const int l = t & 63;
  const int quad = l >> 4;
  const int ln = l & 15;
  const int b = blockIdx.x >> 5;                 // 512 blocks: 16 b * 32 i-tiles
  const int i0 = (blockIdx.x & 31) * 32;

#pragma unroll
  for (int q = 0; q < 4; ++q) {
    int idx = q * 256 + t;
    int r = idx >> 5, c2 = idx & 31;
    adj_lds[r * 33 + c2] = adjb[(i0 + r) * 32 + c2];
  }
  {
    const float4v* src = reinterpret_cast<const float4v*>(e_dstT + (size_t)(b * H_ + w) * N_);
    float4v* dst = reinterpret_cast<float4v*>(&e_lds[w][0]);
#pragma unroll
    for (int q = 0; q < 4; ++q) dst[q * 64 + l] = src[q * 64 + l];
    if (l < 32) es_lds[w][l] = e_srcT[(size_t)(b * H_ + w) * N_ + i0 + l];
  }
  __syncthreads();

  float c[2];
#pragma unroll
  for (int it = 0; it < 2; ++it) c[it] = es_lds[w][it * 16 + ln];

  const unsigned short* slab = hT + (size_t)(b * H_ + w) * 65536;
  const int doff = (quad * 512) + ln * 8;
  float4v acc[2][4];
#pragma unroll
  for (int it = 0; it < 2; ++it)
#pragma unroll
    for (int dt = 0; dt < 4; ++dt) acc[it][dt] = (float4v){0.f, 0.f, 0.f, 0.f};
  float ds[2] = {0.f, 0.f};

  for (int j0 = 0; j0 < N_; j0 += 32) {
    const float* ep = &e_lds[w][j0 + quad * 8];
    float4v e0 = *reinterpret_cast<const float4v*>(ep);
    float4v e1 = *reinterpret_cast<const float4v*>(ep + 4);
    float ej[8] = {e0.x, e0.y, e0.z, e0.w, e1.x, e1.y, e1.z, e1.w};
    unsigned int aw[2];
#pragma unroll
    for (int it = 0; it < 2; ++it) aw[it] = adj_lds[(it * 16 + ln) * 33 + (j0 >> 5)];
    short8 afr[2];
#pragma unroll
    for (int it = 0; it < 2; ++it) {
#pragma unroll
      for (int jj = 0; jj < 8; ++jj) {
        float s = c[it] + ej[jj];
        s = fmaxf(s, NEG * s);                   // leaky relu
        s = fminf(s, 30.f);                      // safety clamp
        float p = ((aw[it] >> (quad * 8 + jj)) & 1u) ? __expf(s) : 0.f;
        ds[it] += p;
        afr[it][jj] = (short)f2bf(p);            // A-frag: row=ln, k=quad*8+jj
      }
    }
    const unsigned short* jbase = slab + (size_t)(j0 >> 3) * 512;
#pragma unroll
    for (int dt = 0; dt < 4; ++dt) {
      short8 bv = *reinterpret_cast<const short8*>(jbase + doff + dt * 128);
#pragma unroll
      for (int it = 0; it < 2; ++it)
        acc[it][dt] = __builtin_amdgcn_mfma_f32_16x16x32_bf16(afr[it], bv, acc[it][dt], 0, 0, 0);
    }
  }

  float inv[2][4];
#pragma unroll
  for (int it = 0; it < 2; ++it) {
    float d2 = ds[it] + __shfl_xor(ds[it], 16, 64);
    d2 += __shfl_xor(d2, 32, 64);
#pragma unroll
    for (int r = 0; r < 4; ++r)
      inv[it][r] = 1.0f / fmaxf(__shfl(d2, quad * 4 + r, 64), 1e-30f);
  }

#pragma unroll
  for (int it = 0; it < 2; ++it) {
#pragma unroll
    for (int dt = 0; dt < 4; ++dt) {
#pragma unroll
      for (int r = 0; r < 4; ++r) {
        int row = i0 + it * 16 + quad * 4 + r;   // C-layout: row=quad*4+reg, col=ln
        int col = w * 64 + dt * 16 + ln;
        out[(size_t)(b * N_ + row) * 256 + col] = acc[it][dt][r] * inv[it][r];
      }
    }
  }
}

// ================= cooperative fallback (R5, verbatim; safety net) =================
__global__ __launch_bounds__(256) void k_gat(const float* x, const int* adj,
                                             const float* W, const float* a_src,
                                             const float* a_dst, float* out) {
  __shared__ float xls[IND * 8];
  __shared__ float e_lds[H_][N_];
  __shared__ float es_lds2[H_][64];
  __shared__ unsigned int adj_lds2[64 * 33];

  const int g = blockIdx.x, t = threadIdx.x, l = t & 63, wv = t >> 6;
  unsigned short* hT = reinterpret_cast<unsigned short*>(out);
  float* e_srcT = out + 2097152;
  float* e_dstT = out + 2162688;
  unsigned int* adjb = reinterpret_cast<unsigned int*>(out + 2228224);

#pragma unroll 4
  for (int q = 0; q < 16; ++q) {
    int f = g * 4096 + q * 256 + t;
    unsigned long long m = __ballot(adj[f] > 0);
    if (l == 0) { adjb[f >> 5] = (unsigned int)m; adjb[(f >> 5) + 1] = (unsigned int)(m >> 32); }
  }
  const int hh = wv, d = l;
  const float asv = a_src[t], adv = a_dst[t];
  for (int u = 0; u < 8; ++u) {
    const int vb = g * 8 + u, b = vb >> 7, n0 = (vb & 127) * 8;
    {
      const float4v v = reinterpret_cast<const float4v*>(x + (size_t)(b * N_ + n0) * IND)[t];
      int e0 = t * 4, r = e0 >> 7, k = e0 & 127;
      float* dst = &xls[k * 8 + r];
      dst[0] = v.x; dst[8] = v.y; dst[16] = v.z; dst[24] = v.w;
    }
    __syncthreads();
    float acc[8] = {0.f, 0.f, 0.f, 0.f, 0.f, 0.f, 0.f, 0.f};
#pragma unroll 4
    for (int k = 0; k < IND; ++k) {
      float wval = W[k * 256 + t];
      const float4v x0 = *reinterpret_cast<const float4v*>(&xls[k * 8]);
      const float4v x1 = *reinterpret_cast<const float4v*>(&xls[k * 8 + 4]);
      acc[0] += x0.x * wval; acc[1] += x0.y * wval; acc[2] += x0.z * wval; acc[3] += x0.w * wval;
      acc[4] += x1.x * wval; acc[5] += x1.y * wval; acc[6] += x1.z * wval; acc[7] += x1.w * wval;
    }
    short8 hs;
#pragma unroll
    for (int r = 0; r < 8; ++r) hs[r] = (short)f2bf(acc[r]);
    *reinterpret_cast<short8*>(hT + ((size_t)(b * H_ + hh) * D_ + d) * N_ + n0) = hs;
#pragma unroll
    for (int r = 0; r < 8; ++r) {
      float es = acc[r] * asv, ed = acc[r] * adv;
#pragma unroll
      for (int m = 1; m < 64; m <<= 1) { es += __shfl_xor(es, m, 64); ed += __shfl_xor(ed, m, 64); }
      if (d == 0) {
        e_srcT[(b * H_ + hh) * N_ + n0 + r] = es;
        e_dstT[(b * H_ + hh) * N_ + n0 + r] = ed;
      }
    }
    __syncthreads();
  }
  cg::this_grid().sync();
  const int w = wv, quad = l >> 4, ln = l & 15, b = g >> 4, i0 = (g & 15) * 64;
#pragma unroll
  for (int q = 0; q < 8; ++q) {
    int idx = q * 256 + t, r = idx >> 5, c2 = idx & 31;
    adj_lds2[r * 33 + c2] = adjb[(i0 + r) * 32 + c2];
  }
  {
    const float4v* src = reinterpret_cast<const float4v*>(e_dstT + (size_t)(b * H_ + w) * N_);
    float4v* dst = reinterpret_cast<float4v*>(&e_lds[w][0]);
#pragma unroll
    for (int q = 0; q < 4; ++q) dst[q * 64 + l] = src[q * 64 + l];
    es_lds2[w][l] = e_srcT[(size_t)(b * H_ + w) * N_ + i0 + l];
  }
  __syncthreads();
  float c[4];
#pragma unroll
  for (int it = 0; it < 4; ++it) c[it] = es_lds2[w][it * 16 + ln];
  const unsigned short* slab = hT + (size_t)(b * H_ + w) * D_ * N_;
  const unsigned short* hb = slab + ln * N_;
  float4v acc[4][4];
#pragma unroll
  for (int it = 0; it < 4; ++it)
#pragma unroll
    for (int dt = 0; dt < 4; ++dt) acc[it][dt] = (float4v){0.f, 0.f, 0.f, 0.f};
  float ds[4] = {0.f, 0.f, 0.f, 0.f};
  for (int j0 = 0; j0 < N_; j0 += 32) {
    const float* ep = &e_lds[w][j0 + quad * 8];
    float4v e0 = *reinterpret_cast<const float4v*>(ep);
    float4v e1 = *reinterpret_cast<const float4v*>(ep + 4);
    float ej[8] = {e0.x, e0.y, e0.z, e0.w, e1.x, e1.y, e1.z, e1.w};
    unsigned int aw[4];
#pragma unroll
    for (int it = 0; it < 4; ++it) aw[it] = adj_lds2[(it * 16 + ln) * 33 + (j0 >> 5)];
    short8 afr[4];
#pragma unroll
    for (int it = 0; it < 4; ++it) {
#pragma unroll
      for (int jj = 0; jj < 8; ++jj) {
        float s = c[it] + ej[jj];
        s = fmaxf(s, NEG * s); s = fminf(s, 30.f);
        float p = ((aw[it] >> (quad * 8 + jj)) & 1u) ? __expf(s) : 0.f;
        ds[it] += p; afr[it][jj] = (short)f2bf(p);
      }
    }
#pragma unroll
    for (int dt = 0; dt < 4; ++dt) {
      short8 bv = *reinterpret_cast<const short8*>(hb + dt * 16 * N_ + j0 + quad * 8);
#pragma unroll
      for (int it = 0; it < 4; ++it)
        acc[it][dt] = __builtin_amdgcn_mfma_f32_16x16x32_bf16(afr[it], bv, acc[it][dt], 0, 0, 0);
    }
  }
  float inv[4][4];
#pragma unroll
  for (int it = 0; it < 4; ++it) {
    float d2 = ds[it] + __shfl_xor(ds[it], 16, 64);
    d2 += __shfl_xor(d2, 32, 64);
#pragma unroll
    for (int r = 0; r < 4; ++r) inv[it][r] = 1.0f / fmaxf(__shfl(d2, quad * 4 + r, 64), 1e-30f);
  }
  cg::this_grid().sync();
#pragma unroll
  for (int it = 0; it < 4; ++it)
#pragma unroll
    for (int dt = 0; dt < 4; ++dt)
#pragma unroll
      for (int r = 0; r < 4; ++r) {
        int row = i0 + it * 16 + quad * 4 + r, col = w * 64 + dt * 16 + ln;
        out[(size_t)(b * N_ + row) * 256 + col] = acc[it][dt][r] * inv[it][r];
      }
}

extern "C" void kernel_launch(void* const* d_in, const int* in_sizes, int n_in,
                              void* d_out, int out_size, void* d_ws, size_t ws_size,
                              hipStream_t stream) {
  const float* x = (const float*)d_in[0];
  const int* adj = (const int*)d_in[1];
  const float* W = (const float*)d_in[2];
  const float* a_src = (const float*)d_in[3];
  const float* a_dst = (const float*)d_in[4];
  float* outp = (float*)d_out;

  if (ws_size >= 9109504u) {
    char* ws = (char*)d_ws;
    unsigned short* hT = (unsigned short*)ws;
    float* e_srcT = (float*)(ws + 8388608);
    float* e_dstT = (float*)(ws + 8650752);
    unsigned int* adjb = (unsigned int*)(ws + 8912896);
    unsigned short* wT = (unsigned short*)(ws + 9043968);
    hipLaunchKernelGGL(k_prep, dim3(4128), dim3(256), 0, stream, adj, W, adjb, wT);
    hipLaunchKernelGGL(k_proj, dim3(512), dim3(256), 0, stream,
                       x, a_src, a_dst, wT, hT, e_srcT, e_dstT);
    hipLaunchKernelGGL(k_attn, dim3(512), dim3(256), 0, stream,
                       hT, e_srcT, e_dstT, adjb, outp);
  } else {
    void* args[] = {(void*)&x, (void*)&adj, (void*)&W, (void*)&a_src, (void*)&a_dst, (void*)&outp};
    hipLaunchCooperativeKernel((void*)k_gat, dim3(256), dim3(256), args, 0u, stream);
  }
}